// Round 8
// baseline (12715.114 us; speedup 1.0000x reference)
//
#include <hip/hip_runtime.h>

typedef unsigned short u16;
typedef _Float16 f16;
typedef __attribute__((ext_vector_type(4))) float f32x4;
typedef __attribute__((ext_vector_type(8))) _Float16 f16x8;
typedef __attribute__((ext_vector_type(8))) unsigned short u16x8;

#define NIMG 8
#define HH 100
#define WW 152
#define HP 102
#define WP 154
#define NPIX (NIMG*HH*WW)                       // 121600
#define ACT_ELEMS ((size_t)NIMG*HP*WP*256)      // 32,169,984
#define ACT_BYTES (ACT_ELEMS*2)

__device__ __forceinline__ u16 f2h(float x){
    f16 h = (f16)x;                       // v_cvt_f16_f32, RNE
    return __builtin_bit_cast(u16, h);
}

__device__ __forceinline__ void g2l16(const u16* g, u16* l){
    __builtin_amdgcn_global_load_lds((const __attribute__((address_space(1))) unsigned int*)g,
                                     (__attribute__((address_space(3))) unsigned int*)l, 16, 0, 0);
}

// ---------------- border zeroing (pads of both ping-pong activation buffers) ----------------
__global__ void zero_borders(u16* A, u16* B){
    int id = blockIdx.x*256 + threadIdx.x;            // 8*508*32 = 130048 exact
    int ch = id & 31; int t = id >> 5;
    int pb = t % 508; int nimg = t / 508;
    int hp, wp;
    if (pb < 154)      { hp = 0;            wp = pb; }
    else if (pb < 308) { hp = 101;          wp = pb - 154; }
    else if (pb < 408) { hp = pb - 308 + 1; wp = 0; }
    else               { hp = pb - 408 + 1; wp = 153; }
    size_t off = ((size_t)((nimg*HP + hp)*WP + wp))*256 + ch*8;
    u16x8 z = {};
    *(u16x8*)(A+off) = z; *(u16x8*)(B+off) = z;
}

// ---------------- NCHW fp32 feature -> padded NHWC fp16 ----------------
__global__ void feat2act(const float* __restrict__ F, u16* __restrict__ D){
    __shared__ float t[64][65];
    int bid = blockIdx.x;
    int wb = bid % 3; bid /= 3;
    int cb = bid & 3; bid >>= 2;
    int h = bid % 100; int nimg = bid / 100;
    int c0 = cb*64, w0 = wb*64;
    int tid = threadIdx.x;
    int cl = tid >> 6;
    int wl = tid & 63;
    #pragma unroll
    for (int rr=0; rr<16; ++rr){
        int c = rr*4 + cl;
        int w = w0 + wl;
        float v = 0.f;
        if (w < WW) v = F[ ((size_t)((nimg*256 + c0 + c)*HH + h))*WW + w ];
        t[c][wl] = v;
    }
    __syncthreads();
    int wl2 = tid >> 6;
    int cl2 = tid & 63;
    #pragma unroll
    for (int rr=0; rr<16; ++rr){
        int w = rr*4 + wl2;
        if (w0 + w < WW){
            size_t dst = ((size_t)((nimg*HP + h + 1)*WP + (w0 + w + 1)))*256 + c0 + cl2;
            D[dst] = f2h(t[cl2][w]);
        }
    }
}

// ---------------- weight transforms: OIHW fp32 -> [tap][co][ci] fp16 ----------------
__global__ void wt_tower(const float* __restrict__ src, u16* __restrict__ d){
    int idx = blockIdx.x*256 + threadIdx.x;        // layers*9*256*256, exact
    int ci = idx & 255; int t = idx >> 8;
    int co = t & 255; t >>= 8;
    int tap = t % 9; int l = t / 9;
    d[idx] = f2h(src[ ((size_t)((l*256+co)*256+ci))*9 + tap ]);
}
// pred(64)+ctn(1) padded to 128 cout
__global__ void wt_predctn(const float* __restrict__ pw, const float* __restrict__ cw,
                           u16* __restrict__ d){
    int idx = blockIdx.x*256 + threadIdx.x;        // 9*128*256 exact (1152 blocks)
    int ci = idx & 255; int co = (idx>>8) & 127; int tap = idx >> 15;
    float v = 0.f;
    if (co < 64)       v = pw[ ((size_t)(co*256+ci))*9 + tap ];
    else if (co == 64) v = cw[ (size_t)ci*9 + tap ];
    d[idx] = f2h(v);
}
// score(1) padded to 128 cout
__global__ void wt_score(const float* __restrict__ sw, u16* __restrict__ d){
    int idx = blockIdx.x*256 + threadIdx.x;        // 9*128*256 exact (1152 blocks)
    int ci = idx & 255; int co = (idx>>8) & 127; int tap = idx >> 15;
    d[idx] = f2h((co == 0) ? sw[ (size_t)ci*9 + tap ] : 0.f);
}
__global__ void prep_bias(const float* pb, const float* cb, const float* sb, float* bpc, float* bsc){
    int i = threadIdx.x;      // 128
    bpc[i] = (i < 64) ? pb[i] : ((i == 64) ? cb[0] : 0.f);
    bsc[i] = (i == 0) ? sb[0] : 0.f;
}

// ---------------- conv3x3 implicit GEMM, fp16, big-wave-tile (MR8xNR8), BK=32 ----------------
// Block 256 threads = 4 waves (2M x 2N).  Tower: block tile 256px x 256co, wave 128x128.
// Heads: block tile 256px x 128co, wave 128x64.  72 K-steps (9 taps x 8 k-blocks of 32).
// LDS per buffer: A[256px][32k] (16 KB) + B[BROWS][32k]; double-buffered (r5's proven
// 2-barrier counted-vmcnt protocol, stage(t+2) into just-read buffer).
// Read swizzle key(p) = (p ^ (p>>2)) & 3 on 16B chunks, applied on BOTH stage-source and
// read side (involution, rule 21) -> conflict-free at the 8-cy wave floor.
// Key property: wave tile 128x128 -> LDS read bytes/MFMA = 256 (r5/r7 were 512).
template<int MODE>
__global__ __launch_bounds__(256, 2) void conv3x3_k(
    const u16* __restrict__ Ain, const u16* __restrict__ W,
    const float* __restrict__ bias,
    u16* __restrict__ Oh, float* __restrict__ O1, float* __restrict__ O2)
{
    constexpr int NR    = (MODE==0) ? 8 : 4;
    constexpr int BROWS = (MODE==0) ? 256 : 128;   // weight co rows
    constexpr int B_ITS = BROWS/64;                // 4 or 2 staging iters
    constexpr int VMN   = 4 + B_ITS;               // loads left in flight at step end
    constexpr int AU16  = 8192;                    // A region u16 (256*32)
    constexpr int BUFU  = AU16 + BROWS*32;         // per-buffer u16
    constexpr int LDSZ  = (MODE==0) ? 33024 : 2*BUFU;   // repack needs 128*258

    __shared__ u16 lds[LDSZ];
    const int tid  = threadIdx.x;
    const int lane = tid & 63;
    const int wave = tid >> 6;

    // bijective XCD swizzle (gridDim.x = 520, %8==0)
    int nwg = gridDim.x;
    int bid = blockIdx.x;
    int qq  = nwg >> 3;
    int swz = (bid & 7)*qq + (bid >> 3);
    int nimg = swz / 65;
    int rem  = swz - nimg*65;
    int ht   = rem / 5;
    int wt5  = rem - ht*5;
    int h0 = ht*8, w0 = wt5*32;          // output tile origin (256 px = 8 rows x 32)

    // A staging source offsets (4 its; slot s: p=s>>2 tile-pixel, ch=s&3 16B chunk)
    int aoff[4];
    #pragma unroll
    for (int it=0; it<4; ++it){
        int s = it*256 + tid;
        int p = s >> 2, ch = s & 3;
        int chs = ch ^ ((p ^ (p >> 2)) & 3);
        int i = p >> 5, j = p & 31;
        int row = h0 + i; if (row > 99)  row = 99;    // clamp (tile overhang; stores masked)
        int col = w0 + j; if (col > 151) col = 151;
        aoff[it] = ((nimg*HP + row)*WP + col)*256 + chs*8;
    }
    // B staging source offsets
    int boff[B_ITS];
    #pragma unroll
    for (int it=0; it<B_ITS; ++it){
        int s = it*256 + tid;
        int p = s >> 2, ch = s & 3;
        int chs = ch ^ ((p ^ (p >> 2)) & 3);
        boff[it] = p*256 + chs*8;
    }
    const int ldst = wave*512;           // wave-uniform LDS dest offset (u16), + it*2048

    // fragment-read lane constants (step-invariant!)
    const int r  = lane & 15;
    const int q4 = lane >> 4;
    const int wm = wave >> 1, wn = wave & 1;
    int aRd[8];
    #pragma unroll
    for (int m=0;m<8;m++){
        int p = wm*128 + m*16 + r;
        aRd[m] = p*32 + ((q4 ^ ((p ^ (p>>2)) & 3)) & 3)*8;
    }
    int bRd[NR];
    #pragma unroll
    for (int n=0;n<NR;n++){
        int p = wn*(NR*16) + n*16 + r;
        bRd[n] = AU16 + p*32 + ((q4 ^ ((p ^ (p>>2)) & 3)) & 3)*8;
    }

    f32x4 acc[8][NR];
    #pragma unroll
    for (int m=0;m<8;m++)
        #pragma unroll
        for (int n=0;n<NR;n++)
            acc[m][n] = (f32x4)0.0f;

    auto stage = [&](int t, int bufbase){
        int tap = t >> 3, kb = t & 7;
        int kh = tap/3, kw = tap - kh*3;
        int adel = (kh*WP + kw)*256 + kb*32;
        int wdel = tap*(BROWS*256) + kb*32;
        u16* L = lds + bufbase;
        #pragma unroll
        for (int it=0; it<4; ++it)
            g2l16(Ain + aoff[it] + adel, L + it*2048 + ldst);
        #pragma unroll
        for (int it=0; it<B_ITS; ++it)
            g2l16(W + wdel + boff[it], L + AU16 + it*2048 + ldst);
    };

    // prologue
    stage(0, 0);
    stage(1, BUFU);
    asm volatile("s_waitcnt vmcnt(%0)" :: "i"(VMN) : "memory");
    __builtin_amdgcn_s_barrier();

    #pragma unroll 1
    for (int t=0; t<72; ++t){
        const int base = (t & 1) ? BUFU : 0;
        const u16* L = lds + base;
        f16x8 af[8], bf[NR];
        #pragma unroll
        for (int m=0;m<8;m++) af[m] = *(const f16x8*)(L + aRd[m]);
        #pragma unroll
        for (int n=0;n<NR;n++) bf[n] = *(const f16x8*)(L + bRd[n]);
        asm volatile("s_waitcnt lgkmcnt(0)" ::: "memory");   // my reads of buf done
        __builtin_amdgcn_s_barrier();                        // all waves done reading buf
        __builtin_amdgcn_sched_barrier(0);
        if (t < 70) stage(t+2, base);                        // WAR-safe overwrite
        __builtin_amdgcn_s_setprio(1);
        #pragma unroll
        for (int n=0;n<NR;n++){
            #pragma unroll
            for (int m=0;m<8;m++){
                acc[m][n] = __builtin_amdgcn_mfma_f32_16x16x32_f16(af[m], bf[n], acc[m][n], 0,0,0);
            }
        }
        __builtin_amdgcn_s_setprio(0);
        __builtin_amdgcn_sched_barrier(0);
        if (t < 70) { asm volatile("s_waitcnt vmcnt(%0)" :: "i"(VMN) : "memory"); }
        else        { asm volatile("s_waitcnt vmcnt(0)" ::: "memory"); }
        __builtin_amdgcn_s_barrier();
    }

    float bcol[NR];
    #pragma unroll
    for (int n=0;n<NR;n++) bcol[n] = bias[wn*(NR*16) + n*16 + r];

    if (MODE == 0){
        // two-pass repack (rows x258 u16 pad) -> relu -> fp16 -> 16B contiguous stores
        #pragma unroll
        for (int P=0; P<2; ++P){
            if (P) __syncthreads();
            #pragma unroll
            for (int m=0;m<4;m++)
                #pragma unroll
                for (int n=0;n<8;n++)
                    #pragma unroll
                    for (int jj=0;jj<4;jj++){
                        float v = fmaxf(acc[P*4+m][n][jj] + bcol[n], 0.f);
                        int lr = wm*64 + m*16 + q4*4 + jj;
                        int c  = wn*128 + n*16 + r;
                        lds[lr*258 + c] = f2h(v);
                    }
            __syncthreads();
            #pragma unroll
            for (int it=0; it<16; ++it){
                int s = it*256 + tid;
                int lr = s >> 5, chh = s & 31;
                int g = (lr >> 6)*128 + P*64 + (lr & 63);
                int i = g >> 5, j = g & 31;
                if (h0 + i < HH && w0 + j < WW){
                    size_t dst = ((size_t)((nimg*HP + h0 + i + 1)*WP + (w0 + j + 1)))*256 + chh*8;
                    *(u16x8*)(Oh + dst) = *(const u16x8*)(lds + lr*258 + chh*8);
                }
            }
        }
    } else {
        #pragma unroll
        for (int m=0;m<8;m++)
            #pragma unroll
            for (int n=0;n<NR;n++)
                #pragma unroll
                for (int jj=0;jj<4;jj++){
                    float v = acc[m][n][jj] + bcol[n];
                    int p = wm*128 + m*16 + q4*4 + jj;
                    int c = wn*64 + n*16 + r;
                    int i = p >> 5, j = p & 31;
                    if (h0 + i < HH && w0 + j < WW){
                        int pix = nimg*(HH*WW) + (h0+i)*WW + (w0+j);
                        if (MODE == 1){
                            if (c < 64)       O1[(size_t)pix*64 + c] = v;
                            else if (c == 64) O2[pix] = v;
                        } else {
                            if (c == 0) O1[pix] = v;
                        }
                    }
                }
    }
}

// ---------------- fused stat (softmax / erf-pmf / top4) + conf 1x1 convs + sigmoid*sigmoid ----------------
__global__ __launch_bounds__(256) void fuse_stat(
    const float* __restrict__ bbox, const float* __restrict__ cls_score,
    const float* __restrict__ w1, const float* __restrict__ b1,
    const float* __restrict__ w2, const float* __restrict__ b2,
    float* __restrict__ pred_cls)
{
    __shared__ float sstat[48][256];
    int tid = threadIdx.x;
    int pix = blockIdx.x*256 + tid;
    if (pix >= NPIX) return;
    const f32x4* row4 = (const f32x4*)(bbox + (size_t)pix*64);
    for (int g=0; g<4; ++g){
        f32x4 v0 = row4[g*4+0], v1 = row4[g*4+1], v2 = row4[g*4+2], v3 = row4[g*4+3];
        float lg[8], ls[8];
        #pragma unroll
        for (int k=0;k<4;k++){ lg[k]=v0[k]; lg[4+k]=v1[k]; ls[k]=v2[k]; ls[4+k]=v3[k]; }
        float m = lg[0];
        #pragma unroll
        for (int k=1;k<8;k++) m = fmaxf(m, lg[k]);
        float e[8], s = 0.f;
        #pragma unroll
        for (int k=0;k<8;k++){ e[k] = expf(lg[k]-m); s += e[k]; }
        float isum = 1.0f/s;
        float prob[8];
        #pragma unroll
        for (int k=0;k<8;k++) prob[k] = e[k]*isum;
        float pmf[8];
        #pragma unroll
        for (int k=0;k<8;k++) pmf[k] = 0.f;
        #pragma unroll
        for (int i=0;i<8;i++){
            float invi = 1.0f/(expf(ls[i]) * 1.41421356237309515f);
            float pi = prob[i];
            #pragma unroll
            for (int j=0;j<8;j++){
                float d = (float)(j - i);
                pmf[j] = fmaf(0.5f*(erff((d+1.0f)*invi) - erff((d-1.0f)*invi)), pi, pmf[j]);
            }
        }
        int used = 0;
        #pragma unroll
        for (int t=0;t<4;t++){
            float bv = -3.0e38f; int bi = 0;
            #pragma unroll
            for (int j=0;j<8;j++){
                bool ok = (((used>>j)&1)==0) && (pmf[j] > bv);
                bv = ok ? pmf[j] : bv;
                bi = ok ? j : bi;
            }
            used |= (1<<bi);
            float sl=0.f, sp=0.f;
            #pragma unroll
            for (int j=0;j<8;j++){ if (j==bi){ sl=ls[j]; sp=prob[j]; } }
            sstat[g*4+t][tid]    = sl;
            sstat[16+g*4+t][tid] = sp;
            sstat[32+g*4+t][tid] = bv;
        }
    }
    float q = b2[0];
    for (int u=0; u<64; ++u){
        float h = b1[u];
        #pragma unroll
        for (int c=0;c<48;c++) h = fmaf(sstat[c][tid], w1[u*48+c], h);
        q = fmaf(fmaxf(h,0.f), w2[u], q);
    }
    float quality = 1.0f/(1.0f+expf(-q));
    float cs = cls_score[pix];
    pred_cls[pix] = quality/(1.0f+expf(-cs));
}

// ---------------- launch ----------------
extern "C" void kernel_launch(void* const* d_in, const int* in_sizes, int n_in,
                              void* d_out, int out_size, void* d_ws, size_t ws_size,
                              hipStream_t stream) {
    (void)in_sizes; (void)n_in; (void)out_size;
    const float* feature = (const float*)d_in[0];
    const float* cls_w   = (const float*)d_in[1];
    const float* cls_b   = (const float*)d_in[2];
    const float* box_w   = (const float*)d_in[3];
    const float* box_b   = (const float*)d_in[4];
    const float* score_w = (const float*)d_in[5];
    const float* score_b = (const float*)d_in[6];
    const float* pred_w  = (const float*)d_in[7];
    const float* pred_b  = (const float*)d_in[8];
    const float* ctn_w   = (const float*)d_in[9];
    const float* ctn_b   = (const float*)d_in[10];
    const float* conf_w1 = (const float*)d_in[11];
    const float* conf_b1 = (const float*)d_in[12];
    const float* conf_w2 = (const float*)d_in[13];
    const float* conf_b2 = (const float*)d_in[14];

    float* out      = (float*)d_out;
    float* pred_cls = out;
    float* pred_reg = out + NPIX;
    float* pred_ctn = out + NPIX + (size_t)NPIX*64;

    char* ws = (char*)d_ws;
    size_t off = 0;
    auto alloc = [&](size_t b){ size_t rr = off; off += (b + 255) & ~(size_t)255; return rr; };
    u16* aA = (u16*)(ws + alloc(ACT_BYTES + 65536));
    u16* aB = (u16*)(ws + alloc(ACT_BYTES + 65536));
    const size_t TWR = (size_t)4*9*256*256;   // tower wt elements
    const size_t HDW = (size_t)9*128*256;     // head wt elements (128-padded)
    u16* wCls = (u16*)(ws + alloc(TWR*2));
    u16* wBox = (u16*)(ws + alloc(TWR*2));
    u16* wSc  = (u16*)(ws + alloc(HDW*2));
    u16* wPc  = (u16*)(ws + alloc(HDW*2));
    float* bPc = (float*)(ws + alloc(128*4));
    float* bSc = (float*)(ws + alloc(128*4));
    float* clsScore = (float*)(ws + alloc((size_t)NPIX*4));
    if (ws_size < off) return;   // insufficient workspace: bail (bench will flag)

    dim3 B(256);
    // prep
    zero_borders<<<508, B, 0, stream>>>(aA, aB);
    wt_tower<<<9216, B, 0, stream>>>(cls_w, wCls);
    wt_tower<<<9216, B, 0, stream>>>(box_w, wBox);
    wt_score<<<1152, B, 0, stream>>>(score_w, wSc);
    wt_predctn<<<1152, B, 0, stream>>>(pred_w, ctn_w, wPc);
    prep_bias<<<1, 128, 0, stream>>>(pred_b, ctn_b, score_b, bPc, bSc);

    const size_t LW = (size_t)9*256*256;      // per-layer tower wt elements
    // cls tower: feat->A, A->B->A->B->A  (box tower re-materializes its own input below)
    feat2act<<<9600, B, 0, stream>>>(feature, aA);
    conv3x3_k<0><<<520, B, 0, stream>>>(aA, wCls+0*LW, cls_b+0*256, aB, nullptr, nullptr);
    conv3x3_k<0><<<520, B, 0, stream>>>(aB, wCls+1*LW, cls_b+1*256, aA, nullptr, nullptr);
    conv3x3_k<0><<<520, B, 0, stream>>>(aA, wCls+2*LW, cls_b+2*256, aB, nullptr, nullptr);
    conv3x3_k<0><<<520, B, 0, stream>>>(aB, wCls+3*LW, cls_b+3*256, aA, nullptr, nullptr);
    // score head (reads x4 in A)
    conv3x3_k<2><<<520, B, 0, stream>>>(aA, wSc, bSc, nullptr, clsScore, nullptr);
    // box tower: feat->B, B->A->B->A->B
    feat2act<<<9600, B, 0, stream>>>(feature, aB);
    conv3x3_k<0><<<520, B, 0, stream>>>(aB, wBox+0*LW, box_b+0*256, aA, nullptr, nullptr);
    conv3x3_k<0><<<520, B, 0, stream>>>(aA, wBox+1*LW, box_b+1*256, aB, nullptr, nullptr);
    conv3x3_k<0><<<520, B, 0, stream>>>(aB, wBox+2*LW, box_b+2*256, aA, nullptr, nullptr);
    conv3x3_k<0><<<520, B, 0, stream>>>(aA, wBox+3*LW, box_b+3*256, aB, nullptr, nullptr);
    // pred + ctn head (reads y4 in B) -> writes pred_reg / pred_ctn directly
    conv3x3_k<1><<<520, B, 0, stream>>>(aB, wPc, bPc, nullptr, pred_reg, pred_ctn);
    // fused stat + conf + final cls
    fuse_stat<<<475, B, 0, stream>>>(pred_reg, clsScore, conf_w1, conf_b1, conf_w2, conf_b2, pred_cls);
}

// Round 9
// 1356.613 us; speedup vs baseline: 9.3727x; 9.3727x over previous
//
#include <hip/hip_runtime.h>

typedef unsigned short u16;
typedef _Float16 f16;
typedef __attribute__((ext_vector_type(4))) float f32x4;
typedef __attribute__((ext_vector_type(8))) _Float16 f16x8;
typedef __attribute__((ext_vector_type(8))) unsigned short u16x8;

#define NIMG 8
#define HH 100
#define WW 152
#define HP 102
#define WP 154
#define NPIX (NIMG*HH*WW)                       // 121600
#define ACT_ELEMS ((size_t)NIMG*HP*WP*256)      // 32,169,984
#define ACT_BYTES (ACT_ELEMS*2)

__device__ __forceinline__ u16 f2h(float x){
    f16 h = (f16)x;                       // v_cvt_f16_f32, RNE
    return __builtin_bit_cast(u16, h);
}

__device__ __forceinline__ void g2l16(const u16* g, u16* l){
    __builtin_amdgcn_global_load_lds((const __attribute__((address_space(1))) unsigned int*)g,
                                     (__attribute__((address_space(3))) unsigned int*)l, 16, 0, 0);
}

// ---------------- border zeroing (pads of all four ping-pong activation buffers) ----------------
__global__ void zero_borders(u16* A, u16* B, u16* C, u16* D){
    int id = blockIdx.x*256 + threadIdx.x;            // 8*508*32 = 130048 exact
    int ch = id & 31; int t = id >> 5;
    int pb = t % 508; int nimg = t / 508;
    int hp, wp;
    if (pb < 154)      { hp = 0;            wp = pb; }
    else if (pb < 308) { hp = 101;          wp = pb - 154; }
    else if (pb < 408) { hp = pb - 308 + 1; wp = 0; }
    else               { hp = pb - 408 + 1; wp = 153; }
    size_t off = ((size_t)((nimg*HP + hp)*WP + wp))*256 + ch*8;
    u16x8 z = {};
    *(u16x8*)(A+off) = z; *(u16x8*)(B+off) = z;
    *(u16x8*)(C+off) = z; *(u16x8*)(D+off) = z;
}

// ---------------- NCHW fp32 feature -> padded NHWC fp16 (both tower inputs, independent chains) ----------------
__global__ void feat2act(const float* __restrict__ F, u16* __restrict__ D1, u16* __restrict__ D2){
    __shared__ float t[64][65];
    int bid = blockIdx.x;
    int wb = bid % 3; bid /= 3;
    int cb = bid & 3; bid >>= 2;
    int h = bid % 100; int nimg = bid / 100;
    int c0 = cb*64, w0 = wb*64;
    int tid = threadIdx.x;
    int cl = tid >> 6;
    int wl = tid & 63;
    #pragma unroll
    for (int rr=0; rr<16; ++rr){
        int c = rr*4 + cl;
        int w = w0 + wl;
        float v = 0.f;
        if (w < WW) v = F[ ((size_t)((nimg*256 + c0 + c)*HH + h))*WW + w ];
        t[c][wl] = v;
    }
    __syncthreads();
    int wl2 = tid >> 6;
    int cl2 = tid & 63;
    #pragma unroll
    for (int rr=0; rr<16; ++rr){
        int w = rr*4 + wl2;
        if (w0 + w < WW){
            u16 h16 = f2h(t[cl2][w]);
            size_t dst = ((size_t)((nimg*HP + h + 1)*WP + (w0 + w + 1)))*256 + c0 + cl2;
            D1[dst] = h16;
            D2[dst] = h16;
        }
    }
}

// ---------------- weight transforms: OIHW fp32 -> [tap][co][ci] fp16 ----------------
// both towers in one dispatch (grid 18432: first half cls, second half box)
__global__ void wt_tower(const float* __restrict__ srcC, const float* __restrict__ srcB,
                         u16* __restrict__ dC, u16* __restrict__ dB){
    int gidx = blockIdx.x*256 + threadIdx.x;       // 2 * 4*9*256*256
    const int HALF = 4*9*256*256;
    const float* src = (gidx < HALF) ? srcC : srcB;
    u16* d           = (gidx < HALF) ? dC : dB;
    int idx = (gidx < HALF) ? gidx : gidx - HALF;
    int ci = idx & 255; int t = idx >> 8;
    int co = t & 255; t >>= 8;
    int tap = t % 9; int l = t / 9;
    d[idx] = f2h(src[ ((size_t)((l*256+co)*256+ci))*9 + tap ]);
}
// pred(64)+ctn(1) padded to 128 cout
__global__ void wt_predctn(const float* __restrict__ pw, const float* __restrict__ cw,
                           u16* __restrict__ d){
    int idx = blockIdx.x*256 + threadIdx.x;        // 9*128*256 exact (1152 blocks)
    int ci = idx & 255; int co = (idx>>8) & 127; int tap = idx >> 15;
    float v = 0.f;
    if (co < 64)       v = pw[ ((size_t)(co*256+ci))*9 + tap ];
    else if (co == 64) v = cw[ (size_t)ci*9 + tap ];
    d[idx] = f2h(v);
}
// score(1) padded to 128 cout
__global__ void wt_score(const float* __restrict__ sw, u16* __restrict__ d){
    int idx = blockIdx.x*256 + threadIdx.x;        // 9*128*256 exact (1152 blocks)
    int ci = idx & 255; int co = (idx>>8) & 127; int tap = idx >> 15;
    d[idx] = f2h((co == 0) ? sw[ (size_t)ci*9 + tap ] : 0.f);
}
__global__ void prep_bias(const float* pb, const float* cb, const float* sb, float* bpc, float* bsc){
    int i = threadIdx.x;      // 128
    bpc[i] = (i < 64) ? pb[i] : ((i == 64) ? cb[0] : 0.f);
    bsc[i] = (i == 0) ? sb[0] : 0.f;
}

// ---------------- conv3x3 implicit GEMM, fp16 single-pass, 128x128 tile, BK=64 ----------------
// r5's proven core (152 us / 993 TF per tower conv), unchanged protocol:
// 2 LDS buffers (A[128][64] + B[128][64] each), per step: ds_read frags -> lgkmcnt(0) ->
// barrier -> stage(t+2, just-read buf) -> MFMA -> vmcnt(8) -> barrier.
// MODE 0: fused dual-tower (tile id selects cls/box pointers), waves 2Mx2N, MR4xNR4.
// MODE 1: pred+ctn head, waves 4M, MR2xNR5 (80 couts); co<64 -> O1[pix*64+co], co==64 -> O2.
// MODE 2: score head, waves 4M, MR2xNR1; co==0 -> O1[pix].
template<int MODE>
__global__ __launch_bounds__(256, 2) void conv3x3_k(
    const u16* __restrict__ Ain0, const u16* __restrict__ Ain1,
    const u16* __restrict__ W0,  const u16* __restrict__ W1,
    const float* __restrict__ bias0, const float* __restrict__ bias1,
    u16* __restrict__ Oh0, u16* __restrict__ Oh1,
    float* __restrict__ O1, float* __restrict__ O2,
    int nPerTower, int NB, int COUTP)
{
    constexpr int MR = (MODE==0) ? 4 : 2;
    constexpr int NR = (MODE==0) ? 4 : ((MODE==1) ? 5 : 1);

    __shared__ u16 lds[32768];   // 64 KiB (2 buffers; buf stride 16384: A@0, B@8192)
    const int tid  = threadIdx.x;
    const int lane = tid & 63;
    const int wave = tid >> 6;

    // bijective XCD swizzle (gridDim.x % 8 == 0)
    int nwg = gridDim.x;
    int bid = blockIdx.x;
    int qq  = nwg >> 3;
    int swz = (bid & 7)*qq + (bid >> 3);
    int tower = (swz >= nPerTower) ? 1 : 0;
    int id = swz - tower*nPerTower;

    const u16* Ain    = tower ? Ain1  : Ain0;
    const u16* W      = tower ? W1    : W0;
    const float* bias = tower ? bias1 : bias0;
    u16* Oh           = tower ? Oh1   : Oh0;

    int nblk = id % NB;
    int mblk = id / NB;
    int nimg = mblk / 125;
    int rem  = mblk - nimg*125;
    int ht   = rem / 5;
    int wt5  = rem - ht*5;
    int h0 = ht*4, w0 = wt5*32;
    int co0 = nblk*128;

    // staging source offsets. slot s: p=s>>3 row, ch=s&7 16B chunk; chs = ch ^ (p&7).
    int aoff[4], boff[4];
    #pragma unroll
    for (int it=0; it<4; ++it){
        int s = it*256 + tid;
        int p = s >> 3, ch = s & 7;
        int chs = ch ^ (p & 7);
        int i = p >> 5, j = p & 31;
        aoff[it] = ((nimg*HP + h0 + i)*WP + (w0 + j))*256 + chs*8;
        boff[it] = (co0 + p)*256 + chs*8;
    }
    const int ldst = wave*512;   // wave-uniform LDS dest (u16), + it*2048

    // fragment-read lane constants
    const int r  = lane & 15;
    const int q4 = lane >> 4;
    const int c0k = ((q4    ) ^ (r & 7)) * 8;   // swizzled k-chunk, kk=0
    const int c1k = ((q4 + 4) ^ (r & 7)) * 8;   // kk=1
    int wm, wn;
    if (MODE == 0){ wm = wave >> 1; wn = wave & 1; } else { wm = wave; wn = 0; }
    const int aBase = (wm*(MR*16) + r)*64;
    const int bBase = 8192 + (wn*64 + r)*64;

    f32x4 acc[MR][NR];
    #pragma unroll
    for (int m=0;m<MR;m++)
        #pragma unroll
        for (int n=0;n<NR;n++)
            acc[m][n] = (f32x4)0.0f;

    auto stage = [&](int t, int b){
        int tap = t >> 2, kb = t & 3;
        int kh = tap/3, kw = tap - kh*3;
        int adel = (kh*WP + kw)*256 + kb*64;
        int bdel = tap*COUTP*256 + kb*64;
        u16* L = lds + b*16384;
        #pragma unroll
        for (int it=0; it<4; ++it)
            g2l16(Ain + aoff[it] + adel, L +        it*2048 + ldst);
        #pragma unroll
        for (int it=0; it<4; ++it)
            g2l16(W + bdel + boff[it], L + 8192 + it*2048 + ldst);
    };

    // prologue: prime both buffers; wait buf0 (buf1's 8 loads stay in flight)
    stage(0, 0);
    stage(1, 1);
    asm volatile("s_waitcnt vmcnt(8)" ::: "memory");
    __builtin_amdgcn_s_barrier();

    for (int t=0; t<36; ++t){
        int b = t & 1;
        const u16* L = lds + b*16384;
        f16x8 a0[MR], a1[MR], b0[NR], b1[NR];
        #pragma unroll
        for (int m=0;m<MR;m++){
            a0[m] = *(const f16x8*)(L + aBase + m*1024 + c0k);
            a1[m] = *(const f16x8*)(L + aBase + m*1024 + c1k);
        }
        #pragma unroll
        for (int n=0;n<NR;n++){
            b0[n] = *(const f16x8*)(L + bBase + n*1024 + c0k);
            b1[n] = *(const f16x8*)(L + bBase + n*1024 + c1k);
        }
        asm volatile("s_waitcnt lgkmcnt(0)" ::: "memory");   // my reads of buf[b] done
        __builtin_amdgcn_s_barrier();                        // ALL waves done reading buf[b]
        __builtin_amdgcn_sched_barrier(0);
        if (t < 34) stage(t+2, b);                           // WAR-safe overwrite of buf[b]
        __builtin_amdgcn_s_setprio(1);
        #pragma unroll
        for (int n=0;n<NR;n++){
            #pragma unroll
            for (int m=0;m<MR;m++){
                acc[m][n] = __builtin_amdgcn_mfma_f32_16x16x32_f16(a0[m], b0[n], acc[m][n], 0,0,0);
                acc[m][n] = __builtin_amdgcn_mfma_f32_16x16x32_f16(a1[m], b1[n], acc[m][n], 0,0,0);
            }
        }
        __builtin_amdgcn_s_setprio(0);
        __builtin_amdgcn_sched_barrier(0);
        if (t < 34) { asm volatile("s_waitcnt vmcnt(8)" ::: "memory"); }  // stage(t+1) landed
        else        { asm volatile("s_waitcnt vmcnt(0)" ::: "memory"); }
        __builtin_amdgcn_s_barrier();                        // buf[b^1] staged for all waves
    }

    float bcol[NR];
    #pragma unroll
    for (int n=0;n<NR;n++) bcol[n] = bias[co0 + wn*64 + n*16 + r];

    if (MODE == 0){
        // acc -> fp16 via LDS repack -> 16B contiguous stores
        #pragma unroll
        for (int m=0;m<MR;m++)
            #pragma unroll
            for (int n=0;n<NR;n++)
                #pragma unroll
                for (int jj=0;jj<4;jj++){
                    float v = fmaxf(acc[m][n][jj] + bcol[n], 0.f);
                    int p = wm*64 + m*16 + q4*4 + jj;
                    int c = wn*64 + n*16 + r;
                    lds[p*128 + c] = f2h(v);
                }
        __syncthreads();
        #pragma unroll
        for (int it=0; it<8; ++it){
            int s = it*256 + tid;
            int p = s >> 4, chh = s & 15;
            int i = p >> 5, j = p & 31;
            if (w0 + j < WW){
                size_t dst = ((size_t)((nimg*HP + h0 + i + 1)*WP + (w0 + j + 1)))*256 + co0 + chh*8;
                *(u16x8*)(Oh + dst) = *(const u16x8*)(lds + p*128 + chh*8);
            }
        }
    } else {
        #pragma unroll
        for (int m=0;m<MR;m++)
            #pragma unroll
            for (int n=0;n<NR;n++)
                #pragma unroll
                for (int jj=0;jj<4;jj++){
                    float v = acc[m][n][jj] + bcol[n];
                    int p = wm*32 + m*16 + q4*4 + jj;
                    int c = n*16 + r;
                    int i = p >> 5, j = p & 31;
                    if (w0 + j < WW){
                        int pix = nimg*(HH*WW) + (h0+i)*WW + (w0+j);
                        if (MODE == 1){
                            if (c < 64)       O1[(size_t)pix*64 + c] = v;
                            else if (c == 64) O2[pix] = v;
                        } else {
                            if (c == 0) O1[pix] = v;
                        }
                    }
                }
    }
}

// ---------------- fused stat (softmax / erf-pmf / top4) + conf 1x1 convs + sigmoid*sigmoid ----------------
__global__ __launch_bounds__(256) void fuse_stat(
    const float* __restrict__ bbox, const float* __restrict__ cls_score,
    const float* __restrict__ w1, const float* __restrict__ b1,
    const float* __restrict__ w2, const float* __restrict__ b2,
    float* __restrict__ pred_cls)
{
    __shared__ float sstat[48][256];
    int tid = threadIdx.x;
    int pix = blockIdx.x*256 + tid;
    if (pix >= NPIX) return;
    const f32x4* row4 = (const f32x4*)(bbox + (size_t)pix*64);
    for (int g=0; g<4; ++g){
        f32x4 v0 = row4[g*4+0], v1 = row4[g*4+1], v2 = row4[g*4+2], v3 = row4[g*4+3];
        float lg[8], ls[8];
        #pragma unroll
        for (int k=0;k<4;k++){ lg[k]=v0[k]; lg[4+k]=v1[k]; ls[k]=v2[k]; ls[4+k]=v3[k]; }
        float m = lg[0];
        #pragma unroll
        for (int k=1;k<8;k++) m = fmaxf(m, lg[k]);
        float e[8], s = 0.f;
        #pragma unroll
        for (int k=0;k<8;k++){ e[k] = expf(lg[k]-m); s += e[k]; }
        float isum = 1.0f/s;
        float prob[8];
        #pragma unroll
        for (int k=0;k<8;k++) prob[k] = e[k]*isum;
        float pmf[8];
        #pragma unroll
        for (int k=0;k<8;k++) pmf[k] = 0.f;
        #pragma unroll
        for (int i=0;i<8;i++){
            float invi = 1.0f/(expf(ls[i]) * 1.41421356237309515f);
            float pi = prob[i];
            #pragma unroll
            for (int j=0;j<8;j++){
                float d = (float)(j - i);
                pmf[j] = fmaf(0.5f*(erff((d+1.0f)*invi) - erff((d-1.0f)*invi)), pi, pmf[j]);
            }
        }
        int used = 0;
        #pragma unroll
        for (int t=0;t<4;t++){
            float bv = -3.0e38f; int bi = 0;
            #pragma unroll
            for (int j=0;j<8;j++){
                bool ok = (((used>>j)&1)==0) && (pmf[j] > bv);
                bv = ok ? pmf[j] : bv;
                bi = ok ? j : bi;
            }
            used |= (1<<bi);
            float sl=0.f, sp=0.f;
            #pragma unroll
            for (int j=0;j<8;j++){ if (j==bi){ sl=ls[j]; sp=prob[j]; } }
            sstat[g*4+t][tid]    = sl;
            sstat[16+g*4+t][tid] = sp;
            sstat[32+g*4+t][tid] = bv;
        }
    }
    float q = b2[0];
    for (int u=0; u<64; ++u){
        float h = b1[u];
        #pragma unroll
        for (int c=0;c<48;c++) h = fmaf(sstat[c][tid], w1[u*48+c], h);
        q = fmaf(fmaxf(h,0.f), w2[u], q);
    }
    float quality = 1.0f/(1.0f+expf(-q));
    float cs = cls_score[pix];
    pred_cls[pix] = quality/(1.0f+expf(-cs));
}

// ---------------- launch ----------------
extern "C" void kernel_launch(void* const* d_in, const int* in_sizes, int n_in,
                              void* d_out, int out_size, void* d_ws, size_t ws_size,
                              hipStream_t stream) {
    (void)in_sizes; (void)n_in; (void)out_size;
    const float* feature = (const float*)d_in[0];
    const float* cls_w   = (const float*)d_in[1];
    const float* cls_b   = (const float*)d_in[2];
    const float* box_w   = (const float*)d_in[3];
    const float* box_b   = (const float*)d_in[4];
    const float* score_w = (const float*)d_in[5];
    const float* score_b = (const float*)d_in[6];
    const float* pred_w  = (const float*)d_in[7];
    const float* pred_b  = (const float*)d_in[8];
    const float* ctn_w   = (const float*)d_in[9];
    const float* ctn_b   = (const float*)d_in[10];
    const float* conf_w1 = (const float*)d_in[11];
    const float* conf_b1 = (const float*)d_in[12];
    const float* conf_w2 = (const float*)d_in[13];
    const float* conf_b2 = (const float*)d_in[14];

    float* out      = (float*)d_out;
    float* pred_cls = out;
    float* pred_reg = out + NPIX;
    float* pred_ctn = out + NPIX + (size_t)NPIX*64;

    char* ws = (char*)d_ws;
    size_t off = 0;
    auto alloc = [&](size_t b){ size_t rr = off; off += (b + 255) & ~(size_t)255; return rr; };
    u16* aA = (u16*)(ws + alloc(ACT_BYTES + 65536));   // cls ping
    u16* aB = (u16*)(ws + alloc(ACT_BYTES + 65536));   // cls pong
    u16* aC = (u16*)(ws + alloc(ACT_BYTES + 65536));   // box ping
    u16* aD = (u16*)(ws + alloc(ACT_BYTES + 65536));   // box pong
    const size_t TWR = (size_t)4*9*256*256;   // tower wt elements
    const size_t HDW = (size_t)9*128*256;     // head wt elements (128-padded)
    u16* wCls = (u16*)(ws + alloc(TWR*2));
    u16* wBox = (u16*)(ws + alloc(TWR*2));
    u16* wSc  = (u16*)(ws + alloc(HDW*2));
    u16* wPc  = (u16*)(ws + alloc(HDW*2));
    float* bPc = (float*)(ws + alloc(128*4));
    float* bSc = (float*)(ws + alloc(128*4));
    float* clsScore = (float*)(ws + alloc((size_t)NPIX*4));
    if (ws_size < off) return;   // insufficient workspace: bail (bench will flag)

    dim3 B(256);
    // prep
    zero_borders<<<508, B, 0, stream>>>(aA, aB, aC, aD);
    wt_tower<<<18432, B, 0, stream>>>(cls_w, box_w, wCls, wBox);
    wt_score<<<1152, B, 0, stream>>>(score_w, wSc);
    wt_predctn<<<1152, B, 0, stream>>>(pred_w, ctn_w, wPc);
    prep_bias<<<1, 128, 0, stream>>>(pred_b, ctn_b, score_b, bPc, bSc);

    const size_t LW = (size_t)9*256*256;      // per-layer tower wt elements
    // single feature transform feeds both (independent) tower chains
    feat2act<<<9600, B, 0, stream>>>(feature, aA, aC);
    // fused dual-tower layers: cls A<->B, box C<->D  (4000 blocks: first 2000 cls, rest box)
    conv3x3_k<0><<<4000, B, 0, stream>>>(aA, aC, wCls+0*LW, wBox+0*LW, cls_b+0*256, box_b+0*256, aB, aD, nullptr, nullptr, 2000, 2, 256);
    conv3x3_k<0><<<4000, B, 0, stream>>>(aB, aD, wCls+1*LW, wBox+1*LW, cls_b+1*256, box_b+1*256, aA, aC, nullptr, nullptr, 2000, 2, 256);
    conv3x3_k<0><<<4000, B, 0, stream>>>(aA, aC, wCls+2*LW, wBox+2*LW, cls_b+2*256, box_b+2*256, aB, aD, nullptr, nullptr, 2000, 2, 256);
    conv3x3_k<0><<<4000, B, 0, stream>>>(aB, aD, wCls+3*LW, wBox+3*LW, cls_b+3*256, box_b+3*256, aA, aC, nullptr, nullptr, 2000, 2, 256);
    // score head (reads cls x4 in A)
    conv3x3_k<2><<<1000, B, 0, stream>>>(aA, aA, wSc, wSc, bSc, bSc, nullptr, nullptr, clsScore, nullptr, 1000, 1, 128);
    // pred + ctn head (reads box y4 in C) -> writes pred_reg / pred_ctn directly
    conv3x3_k<1><<<1000, B, 0, stream>>>(aC, aC, wPc, wPc, bPc, bPc, nullptr, nullptr, pred_reg, pred_ctn, 1000, 1, 128);
    // fused stat + conf + final cls
    fuse_stat<<<475, B, 0, stream>>>(pred_reg, clsScore, conf_w1, conf_b1, conf_w2, conf_b2, pred_cls);
}